// Round 1
// baseline (588.529 us; speedup 1.0000x reference)
//
#include <hip/hip_runtime.h>

#define T_STEPS 256
#define BATCH   1000
#define D_IN    300
#define H4      8
#define ROWS    32
#define TILE_F4 2400          // ROWS * D_IN / 4 float4 per tile
#define NT      8             // tiles per persistent block
#define NBLK    1000          // NBLK*NT*ROWS = 256000 rows = T*B

#define L2E   1.4426950408889634f   // log2(e)
#define L2E2  2.8853900817779268f   // 2*log2(e)

// ---------------------------------------------------------------------------
// helpers
// ---------------------------------------------------------------------------
__device__ __forceinline__ float fexp2(float x) {
#if __has_builtin(__builtin_amdgcn_exp2f)
    return __builtin_amdgcn_exp2f(x);     // raw v_exp_f32
#else
    return exp2f(x);
#endif
}
// sigmoid with pre-scaled input x' = log2(e)*x
__device__ __forceinline__ float sig2(float x) {
    return __builtin_amdgcn_rcpf(1.0f + fexp2(-x));      // exp2(-x): free neg mod
}
// tanh with pre-scaled input x' = 2*log2(e)*x ; exact limits at +-inf
__device__ __forceinline__ float tanh2(float x) {
    return fmaf(-2.0f, __builtin_amdgcn_rcpf(1.0f + fexp2(x)), 1.0f);
}

// async global->LDS DMA, 16B per lane; lds dst must be wave-uniform base
__device__ __forceinline__ void gload16(const float4* g, float4* l) {
    __builtin_amdgcn_global_load_lds(
        (const __attribute__((address_space(1))) void*)g,
        (__attribute__((address_space(3))) void*)l, 16, 0, 0);
}

// ---------------------------------------------------------------------------
// Kernel A: xg[row,g] = (dot(x[row,:], W_ih0[g,:]) + b) * gate_scale[g]
// Persistent blocks, NT=8 tiles each, double-buffered LDS staged with
// global_load_lds(16B) and COUNTED vmcnt (never a full drain in the loop):
// stage(i+1) issued before compute(i), wait vmcnt(1) (allow the out-store)
// + raw s_barrier at tile end.  1 block/CU (92KB LDS); HBM stays busy
// through the compute phase -> BW-bound at ~307MB mandatory traffic.
// Tail of the ragged 2400-f4 tile is handled by CLAMPING the global source
// (uniform 10 DMA ops per wave -> exact vmcnt bookkeeping); clamped lanes
// write into the LDS pad region [2400,2560) which is never read.
// gate_scale folds log2(e) (2*log2(e) for cell gates 4,5) into the gate
// pre-activations so kernel B can use raw v_exp_f32 (exp2) activations.
// ---------------------------------------------------------------------------
__global__ __launch_bounds__(256) void xproj_kernel(
    const float* __restrict__ x, const float* __restrict__ W,
    const float* __restrict__ b_ih, const float* __restrict__ b_hh,
    float* __restrict__ xg)
{
    __shared__ __align__(16) float xs[2][2560 * 4];   // 2 x 40.96 KB (incl. pad)
    __shared__ __align__(16) float ws[768 * 4];       // 12.29 KB (incl. pad)

    const int tid   = threadIdx.x;
    const int wbase = tid & ~63;            // wave-uniform lds index base

    const float4* xf4 = (const float4*)x;
    const float4* wf4 = (const float4*)W;
    float4* xs0 = (float4*)xs[0];
    float4* xs1 = (float4*)xs[1];
    float4* wsf = (float4*)ws;

    const long tile0 = (long)blockIdx.x * NT;

    const int g = tid & 7;
    const int r = tid >> 3;
    // issued before the vmcnt(0) drain -> never outstanding inside the loop
    const float bias  = b_ih[g] + b_hh[g];
    const float scale = (g == 4 || g == 5) ? L2E2 : L2E;   // cell gates: 2*log2e

    // ---- prologue: stage W (3 ops/wave) + tile0 (10 ops/wave) ----
#pragma unroll
    for (int j = 0; j < 3; ++j) {
        int k  = j * 256 + tid;
        int gk = k < 600 ? k : 599;                       // clamp source
        gload16(wf4 + gk, wsf + (j * 256 + wbase));
    }
#pragma unroll
    for (int j = 0; j < 10; ++j) {
        int k  = j * 256 + tid;
        int gk = k < TILE_F4 ? k : TILE_F4 - 1;
        gload16(xf4 + tile0 * TILE_F4 + gk, xs0 + (j * 256 + wbase));
    }
    asm volatile("s_waitcnt vmcnt(0)" ::: "memory");
    __builtin_amdgcn_s_barrier();

    const float4* wr = wsf + g * 75;

    for (int i = 0; i < NT; ++i) {
        // issue next tile's DMA before computing current (pipeline)
        if (i + 1 < NT) {
            float4* nbuf = (i & 1) ? xs0 : xs1;
            long tb = (tile0 + i + 1) * TILE_F4;
#pragma unroll
            for (int j = 0; j < 10; ++j) {
                int k  = j * 256 + tid;
                int gk = k < TILE_F4 ? k : TILE_F4 - 1;
                gload16(xf4 + tb + gk, nbuf + (j * 256 + wbase));
            }
        }

        const float4* xr = ((i & 1) ? xs1 : xs0) + r * 75;
        float a0 = 0.f, a1 = 0.f, a2 = 0.f, a3 = 0.f;
#pragma unroll 5
        for (int k = 0; k < 75; ++k) {
            float4 xv = xr[k];
            float4 wv = wr[k];
            a0 += xv.x * wv.x; a1 += xv.y * wv.y;
            a2 += xv.z * wv.z; a3 += xv.w * wv.w;
        }
        // out index = (tile*32 + r)*8 + g = tile*256 + tid -> coalesced
        xg[(tile0 + i) * 256 + tid] = ((a0 + a1) + (a2 + a3) + bias) * scale;

        if (i + 1 < NT) {
            // allow the newest 1 op (our out-store) to stay in flight;
            // guarantees tile i+1's 10 DMA loads have landed.
            asm volatile("s_waitcnt vmcnt(1)" ::: "memory");
            __builtin_amdgcn_s_barrier();
        }
    }
}

// ---------------------------------------------------------------------------
// Kernel B: sequential 2-layer LSTM scan + final linear, one thread/batch elem.
// Gate pre-activations arrive pre-scaled by log2e (2*log2e for cell gates),
// and the register-resident weights/biases are scaled identically, so every
// activation is exp2-direct: sigmoid = rcp(1+exp2(-x)), tanh = 1-2*rcp(1+exp2(x))
// -- no multiply on the dependent chain. Cell states stay in the normal domain
// (one mul by 2*log2e feeds their tanh). Depth-4 prefetch + h1-partial hoist
// kept from the previous version.
// ---------------------------------------------------------------------------
__global__ __launch_bounds__(64) void lstm_seq_kernel(
    const float* __restrict__ xg,
    const float* __restrict__ h0in, const float* __restrict__ c0in,
    const float* __restrict__ Whh0, const float* __restrict__ Wih1,
    const float* __restrict__ Whh1, const float* __restrict__ bih1,
    const float* __restrict__ bhh1, const float* __restrict__ Wlin,
    const float* __restrict__ blin, float* __restrict__ out)
{
    int b = blockIdx.x * 64 + threadIdx.x;
    bool active = (b < BATCH);
    int bb = active ? b : (BATCH - 1);   // clamp: harmless compute, no store

    // Tiny weights -> registers, pre-scaled into the exp2 domain.
    float whh0[H4][2], wih1[H4][2], whh1[H4][2], bias1[H4];
#pragma unroll
    for (int k = 0; k < H4; ++k) {
        float f = (k == 4 || k == 5) ? L2E2 : L2E;
        whh0[k][0] = Whh0[2 * k] * f; whh0[k][1] = Whh0[2 * k + 1] * f;
        wih1[k][0] = Wih1[2 * k] * f; wih1[k][1] = Wih1[2 * k + 1] * f;
        whh1[k][0] = Whh1[2 * k] * f; whh1[k][1] = Whh1[2 * k + 1] * f;
        bias1[k]   = (bih1[k] + bhh1[k]) * f;
    }

    // Initial state (inputs are [LAYERS, B, H])
    float h0a = h0in[2 * bb],             h0b = h0in[2 * bb + 1];
    float c0a = c0in[2 * bb],             c0b = c0in[2 * bb + 1];
    float h1a = h0in[2 * BATCH + 2 * bb], h1b = h0in[2 * BATCH + 2 * bb + 1];
    float c1a = c0in[2 * BATCH + 2 * bb], c1b = c0in[2 * BATCH + 2 * bb + 1];

    const float4* __restrict__ xp = (const float4*)xg;

    // depth-4 software pipeline on the per-step gate loads (32 B/step)
    float4 plo[4], phi[4];
#pragma unroll
    for (int t = 0; t < 4; ++t) {
        plo[t] = xp[(t * BATCH + bb) * 2];
        phi[t] = xp[(t * BATCH + bb) * 2 + 1];
    }

    // Layer-1 partial gates (h1-dependent half), hoisted across steps.
    float p[H4];
#pragma unroll
    for (int k = 0; k < H4; ++k)
        p[k] = bias1[k] + h1a * whh1[k][0] + h1b * whh1[k][1];

#pragma unroll 4
    for (int t = 0; t < T_STEPS; ++t) {
        int s = t & 3;
        float4 l4 = plo[s], h4 = phi[s];
        if (t + 4 < T_STEPS) {
            plo[s] = xp[((t + 4) * BATCH + bb) * 2];
            phi[s] = xp[((t + 4) * BATCH + bb) * 2 + 1];
        }
        float xv[H4] = {l4.x, l4.y, l4.z, l4.w, h4.x, h4.y, h4.z, h4.w};

        // ----- layer 0: gates = xg' + h @ Whh0'^T (order: i i f f g g o o) --
        float gt[H4];
#pragma unroll
        for (int k = 0; k < H4; ++k)
            gt[k] = xv[k] + h0a * whh0[k][0] + h0b * whh0[k][1];
        c0a = sig2(gt[2]) * c0a + sig2(gt[0]) * tanh2(gt[4]);
        c0b = sig2(gt[3]) * c0b + sig2(gt[1]) * tanh2(gt[5]);
        h0a = sig2(gt[6]) * tanh2(c0a * L2E2);
        h0b = sig2(gt[7]) * tanh2(c0b * L2E2);

        // ----- layer 1: q = p (precomputed) + h0-dependent half -------------
        float qt[H4];
#pragma unroll
        for (int k = 0; k < H4; ++k)
            qt[k] = p[k] + h0a * wih1[k][0] + h0b * wih1[k][1];
        c1a = sig2(qt[2]) * c1a + sig2(qt[0]) * tanh2(qt[4]);
        c1b = sig2(qt[3]) * c1b + sig2(qt[1]) * tanh2(qt[5]);
        h1a = sig2(qt[6]) * tanh2(c1a * L2E2);
        h1b = sig2(qt[7]) * tanh2(c1b * L2E2);

        // hoist next step's h1-dependent layer-1 partials
#pragma unroll
        for (int k = 0; k < H4; ++k)
            p[k] = bias1[k] + h1a * whh1[k][0] + h1b * whh1[k][1];
    }

    if (active)
        out[b] = h1a * Wlin[0] + h1b * Wlin[1] + blin[0];
}

extern "C" void kernel_launch(void* const* d_in, const int* in_sizes, int n_in,
                              void* d_out, int out_size, void* d_ws, size_t ws_size,
                              hipStream_t stream) {
    const float* x      = (const float*)d_in[0];
    const float* h0     = (const float*)d_in[1];
    const float* c0     = (const float*)d_in[2];
    const float* W_ih0  = (const float*)d_in[3];
    const float* W_hh0  = (const float*)d_in[4];
    const float* b_ih0  = (const float*)d_in[5];
    const float* b_hh0  = (const float*)d_in[6];
    const float* W_ih1  = (const float*)d_in[7];
    const float* W_hh1  = (const float*)d_in[8];
    const float* b_ih1  = (const float*)d_in[9];
    const float* b_hh1  = (const float*)d_in[10];
    const float* W_lin  = (const float*)d_in[11];
    const float* b_lin  = (const float*)d_in[12];
    float* out = (float*)d_out;
    float* xg  = (float*)d_ws;   // T*B*8 floats = 8.192 MB

    xproj_kernel<<<NBLK, 256, 0, stream>>>(x, W_ih0, b_ih0, b_hh0, xg);
    lstm_seq_kernel<<<(BATCH + 63) / 64, 64, 0, stream>>>(
        xg, h0, c0, W_hh0, W_ih1, W_hh1, b_ih1, b_hh1, W_lin, b_lin, out);
}

// Round 3
// 555.829 us; speedup vs baseline: 1.0588x; 1.0588x over previous
//
#include <hip/hip_runtime.h>

#define T_STEPS 256
#define BATCH   1000
#define D_IN    300
#define H4      8
#define NF4     75            // float4 per row (300 floats)
#define RPB     128           // rows per block (64 quads x 2 rows)
#define NBLK    2000          // 2000 * 128 = 256000 rows = T*B

#define L2E   1.4426950408889634f   // log2(e)
#define L2E2  2.8853900817779268f   // 2*log2(e)

// ---------------------------------------------------------------------------
// helpers
// ---------------------------------------------------------------------------
__device__ __forceinline__ float fexp2(float x) {
#if __has_builtin(__builtin_amdgcn_exp2f)
    return __builtin_amdgcn_exp2f(x);     // raw v_exp_f32
#else
    return exp2f(x);
#endif
}
// sigmoid with pre-scaled input x' = log2(e)*x
__device__ __forceinline__ float sig2(float x) {
    return __builtin_amdgcn_rcpf(1.0f + fexp2(-x));      // exp2(-x): free neg mod
}
// tanh with pre-scaled input x' = 2*log2(e)*x ; exact limits at +-inf
__device__ __forceinline__ float tanh2(float x) {
    return fmaf(-2.0f, __builtin_amdgcn_rcpf(1.0f + fexp2(x)), 1.0f);
}

__device__ __forceinline__ float dot4acc(float4 a, float4 b, float acc) {
    return fmaf(a.x, b.x, fmaf(a.y, b.y, fmaf(a.z, b.z, fmaf(a.w, b.w, acc))));
}

// ---------------------------------------------------------------------------
// Kernel A (v3): xg[row,g] = (dot(x[row,:], W_ih0[g,:]) + b) * gate_scale[g]
//
// Decomposition inverted vs v1/v2: a 4-lane quad owns TWO rows and computes
// ALL 8 gates, so each x element is loaded exactly once, HBM -> VGPR direct
// (no x staging, no 8x LDS re-read -- that LDS read pipe was the old
// bottleneck at ~7200 cyc/tile vs 4000 cyc of HBM time).
//   lane l of a quad reads float4 k = 4*i + l  -> the quad's 4 lanes cover
//   one full 64B line per row per instruction: zero coalescing waste and no
//   L1-reuse dependence (every fetched line is fully consumed immediately).
// W (9.6 KB) is the only LDS user, staged once; per-iteration W reads have
// only 4 unique addresses per wave (16-way broadcast, conflict-free).
// Quad-local butterfly (__shfl_xor 1,2) finishes the dot; each lane then
// stores 2 gates per row as a coalesced float2.
// gate_scale folds log2(e) (2*log2(e) for cell gates 4,5) into the gate
// pre-activations so kernel B can use raw v_exp_f32 (exp2) activations.
// ---------------------------------------------------------------------------
__global__ __launch_bounds__(256) void xproj_kernel(
    const float* __restrict__ x, const float* __restrict__ W,
    const float* __restrict__ b_ih, const float* __restrict__ b_hh,
    float* __restrict__ xg)
{
    __shared__ __align__(16) float4 ws4[H4 * NF4];   // 9.6 KB

    const int tid = threadIdx.x;
    const float4* __restrict__ w4 = (const float4*)W;
    for (int k = tid; k < H4 * NF4; k += 256)
        ws4[k] = w4[k];
    __syncthreads();

    const int  lane = tid & 3;
    const int  quad = tid >> 2;
    const long row0 = (long)blockIdx.x * RPB + (long)quad * 2;

    const float4* __restrict__ x0 = (const float4*)x + row0 * NF4;
    const float4* __restrict__ x1 = x0 + NF4;

    float acc0[H4], acc1[H4];
#pragma unroll
    for (int g = 0; g < H4; ++g) { acc0[g] = 0.f; acc1[g] = 0.f; }

    // main loop: i = 0..17, k = 4i+lane <= 71+3 < 75 -> no guard needed
#pragma unroll 3
    for (int i = 0; i < 18; ++i) {
        const int k = 4 * i + lane;
        float4 xa = x0[k];
        float4 xb = x1[k];
#pragma unroll
        for (int g = 0; g < H4; ++g) {
            float4 wv = ws4[g * NF4 + k];
            acc0[g] = dot4acc(xa, wv, acc0[g]);
            acc1[g] = dot4acc(xb, wv, acc1[g]);
        }
    }
    // epilogue: i = 18 -> k = 72+lane, valid only for lane < 3
    {
        const int k = 72 + lane;
        if (k < NF4) {
            float4 xa = x0[k];
            float4 xb = x1[k];
#pragma unroll
            for (int g = 0; g < H4; ++g) {
                float4 wv = ws4[g * NF4 + k];
                acc0[g] = dot4acc(xa, wv, acc0[g]);
                acc1[g] = dot4acc(xb, wv, acc1[g]);
            }
        }
    }

    // quad-local butterfly reduction (xor 1, xor 2 stay within the quad)
#pragma unroll
    for (int g = 0; g < H4; ++g) {
        acc0[g] += __shfl_xor(acc0[g], 1);
        acc0[g] += __shfl_xor(acc0[g], 2);
        acc1[g] += __shfl_xor(acc1[g], 1);
        acc1[g] += __shfl_xor(acc1[g], 2);
    }

    // lane writes gates {2*lane, 2*lane+1} for both rows, coalesced float2.
    // gate order i i f f g g o o: lane 2 owns the cell gates -> scale 2*log2e
    const int   g0 = lane * 2;
    const float b0 = b_ih[g0]     + b_hh[g0];
    const float b1 = b_ih[g0 + 1] + b_hh[g0 + 1];
    const float sc = (lane == 2) ? L2E2 : L2E;

    float2* __restrict__ out2 = (float2*)xg;
    float2 o0 = { (acc0[g0] + b0) * sc, (acc0[g0 + 1] + b1) * sc };
    float2 o1 = { (acc1[g0] + b0) * sc, (acc1[g0 + 1] + b1) * sc };
    out2[row0 * 4 + lane]       = o0;
    out2[(row0 + 1) * 4 + lane] = o1;
}

// ---------------------------------------------------------------------------
// Kernel B: sequential 2-layer LSTM scan + final linear, one thread/batch elem.
// Gate pre-activations arrive pre-scaled by log2e (2*log2e for cell gates),
// and the register-resident weights/biases are scaled identically, so every
// activation is exp2-direct: sigmoid = rcp(1+exp2(-x)), tanh = 1-2*rcp(1+exp2(x))
// -- no multiply on the dependent chain. Cell states stay in the normal domain
// (one mul by 2*log2e feeds their tanh). Depth-4 prefetch + h1-partial hoist.
// ---------------------------------------------------------------------------
__global__ __launch_bounds__(64) void lstm_seq_kernel(
    const float* __restrict__ xg,
    const float* __restrict__ h0in, const float* __restrict__ c0in,
    const float* __restrict__ Whh0, const float* __restrict__ Wih1,
    const float* __restrict__ Whh1, const float* __restrict__ bih1,
    const float* __restrict__ bhh1, const float* __restrict__ Wlin,
    const float* __restrict__ blin, float* __restrict__ out)
{
    int b = blockIdx.x * 64 + threadIdx.x;
    bool active = (b < BATCH);
    int bb = active ? b : (BATCH - 1);   // clamp: harmless compute, no store

    // Tiny weights -> registers, pre-scaled into the exp2 domain.
    float whh0[H4][2], wih1[H4][2], whh1[H4][2], bias1[H4];
#pragma unroll
    for (int k = 0; k < H4; ++k) {
        float f = (k == 4 || k == 5) ? L2E2 : L2E;
        whh0[k][0] = Whh0[2 * k] * f; whh0[k][1] = Whh0[2 * k + 1] * f;
        wih1[k][0] = Wih1[2 * k] * f; wih1[k][1] = Wih1[2 * k + 1] * f;
        whh1[k][0] = Whh1[2 * k] * f; whh1[k][1] = Whh1[2 * k + 1] * f;
        bias1[k]   = (bih1[k] + bhh1[k]) * f;
    }

    // Initial state (inputs are [LAYERS, B, H])
    float h0a = h0in[2 * bb],             h0b = h0in[2 * bb + 1];
    float c0a = c0in[2 * bb],             c0b = c0in[2 * bb + 1];
    float h1a = h0in[2 * BATCH + 2 * bb], h1b = h0in[2 * BATCH + 2 * bb + 1];
    float c1a = c0in[2 * BATCH + 2 * bb], c1b = c0in[2 * BATCH + 2 * bb + 1];

    const float4* __restrict__ xp = (const float4*)xg;

    // depth-4 software pipeline on the per-step gate loads (32 B/step)
    float4 plo[4], phi[4];
#pragma unroll
    for (int t = 0; t < 4; ++t) {
        plo[t] = xp[(t * BATCH + bb) * 2];
        phi[t] = xp[(t * BATCH + bb) * 2 + 1];
    }

    // Layer-1 partial gates (h1-dependent half), hoisted across steps.
    float p[H4];
#pragma unroll
    for (int k = 0; k < H4; ++k)
        p[k] = bias1[k] + h1a * whh1[k][0] + h1b * whh1[k][1];

#pragma unroll 4
    for (int t = 0; t < T_STEPS; ++t) {
        int s = t & 3;
        float4 l4 = plo[s], h4 = phi[s];
        if (t + 4 < T_STEPS) {
            plo[s] = xp[((t + 4) * BATCH + bb) * 2];
            phi[s] = xp[((t + 4) * BATCH + bb) * 2 + 1];
        }
        float xv[H4] = {l4.x, l4.y, l4.z, l4.w, h4.x, h4.y, h4.z, h4.w};

        // ----- layer 0: gates = xg' + h @ Whh0'^T (order: i i f f g g o o) --
        float gt[H4];
#pragma unroll
        for (int k = 0; k < H4; ++k)
            gt[k] = xv[k] + h0a * whh0[k][0] + h0b * whh0[k][1];
        c0a = sig2(gt[2]) * c0a + sig2(gt[0]) * tanh2(gt[4]);
        c0b = sig2(gt[3]) * c0b + sig2(gt[1]) * tanh2(gt[5]);
        h0a = sig2(gt[6]) * tanh2(c0a * L2E2);
        h0b = sig2(gt[7]) * tanh2(c0b * L2E2);

        // ----- layer 1: q = p (precomputed) + h0-dependent half -------------
        float qt[H4];
#pragma unroll
        for (int k = 0; k < H4; ++k)
            qt[k] = p[k] + h0a * wih1[k][0] + h0b * wih1[k][1];
        c1a = sig2(qt[2]) * c1a + sig2(qt[0]) * tanh2(qt[4]);
        c1b = sig2(qt[3]) * c1b + sig2(qt[1]) * tanh2(qt[5]);
        h1a = sig2(qt[6]) * tanh2(c1a * L2E2);
        h1b = sig2(qt[7]) * tanh2(c1b * L2E2);

        // hoist next step's h1-dependent layer-1 partials
#pragma unroll
        for (int k = 0; k < H4; ++k)
            p[k] = bias1[k] + h1a * whh1[k][0] + h1b * whh1[k][1];
    }

    if (active)
        out[b] = h1a * Wlin[0] + h1b * Wlin[1] + blin[0];
}

extern "C" void kernel_launch(void* const* d_in, const int* in_sizes, int n_in,
                              void* d_out, int out_size, void* d_ws, size_t ws_size,
                              hipStream_t stream) {
    const float* x      = (const float*)d_in[0];
    const float* h0     = (const float*)d_in[1];
    const float* c0     = (const float*)d_in[2];
    const float* W_ih0  = (const float*)d_in[3];
    const float* W_hh0  = (const float*)d_in[4];
    const float* b_ih0  = (const float*)d_in[5];
    const float* b_hh0  = (const float*)d_in[6];
    const float* W_ih1  = (const float*)d_in[7];
    const float* W_hh1  = (const float*)d_in[8];
    const float* b_ih1  = (const float*)d_in[9];
    const float* b_hh1  = (const float*)d_in[10];
    const float* W_lin  = (const float*)d_in[11];
    const float* b_lin  = (const float*)d_in[12];
    float* out = (float*)d_out;
    float* xg  = (float*)d_ws;   // T*B*8 floats = 8.192 MB

    xproj_kernel<<<NBLK, 256, 0, stream>>>(x, W_ih0, b_ih0, b_hh0, xg);
    lstm_seq_kernel<<<(BATCH + 63) / 64, 64, 0, stream>>>(
        xg, h0, c0, W_hh0, W_ih1, W_hh1, b_ih1, b_hh1, W_lin, b_lin, out);
}

// Round 4
// 498.490 us; speedup vs baseline: 1.1806x; 1.1150x over previous
//
#include <hip/hip_runtime.h>

#define T_STEPS 256
#define BATCH   1000
#define D_IN    300
#define H4      8
#define NF4     75            // float4 per row (300 floats)
#define RPB     128           // rows per block (64 quads x 2 rows)
#define NBLK    2000          // 2000 * 128 = 256000 rows = T*B

#define L2E   1.4426950408889634f   // log2(e)
#define L2E2  2.8853900817779268f   // 2*log2(e)

// ---------------------------------------------------------------------------
// helpers
// ---------------------------------------------------------------------------
__device__ __forceinline__ float fexp2(float x) {
#if __has_builtin(__builtin_amdgcn_exp2f)
    return __builtin_amdgcn_exp2f(x);     // raw v_exp_f32
#else
    return exp2f(x);
#endif
}
// sigmoid with pre-scaled input x' = log2(e)*x
__device__ __forceinline__ float sig2(float x) {
    return __builtin_amdgcn_rcpf(1.0f + fexp2(-x));      // exp2(-x): free neg mod
}
// tanh with pre-scaled input x' = 2*log2(e)*x ; exact limits at +-inf
__device__ __forceinline__ float tanh2(float x) {
    return fmaf(-2.0f, __builtin_amdgcn_rcpf(1.0f + fexp2(x)), 1.0f);
}

__device__ __forceinline__ float dot4acc(float4 a, float4 b, float acc) {
    return fmaf(a.x, b.x, fmaf(a.y, b.y, fmaf(a.z, b.z, fmaf(a.w, b.w, acc))));
}

// swap adjacent lanes (0<->1, 2<->3) via DPP quad_perm [1,0,3,2]: pure VALU,
// no LDS round-trip. All lanes are active for the whole kernel, so exec-mask
// corner cases don't arise.
__device__ __forceinline__ float swap1(float x) {
#if __has_builtin(__builtin_amdgcn_mov_dpp)
    return __int_as_float(
        __builtin_amdgcn_mov_dpp(__float_as_int(x), 0xB1, 0xF, 0xF, true));
#else
    return __shfl_xor(x, 1);
#endif
}

// ---------------------------------------------------------------------------
// Kernel A (v4): xg[row][u][s] = (dot(x[row,:], W_ih0[2s+u,:]) + b) * scale
//   (s = gate slot i,f,g,o ; u = hidden unit 0/1)
// Same inverted decomposition as v3 (x read once, HBM -> VGPR direct; quad
// owns 2 rows x all 8 gates; W broadcast from 9.6 KB LDS; quad butterfly).
// Only change: the OUTPUT LAYOUT groups gates by unit so kernel B's lane
// (element e, unit u) loads its whole step input as one float4.
// gate_scale folds log2(e) (2*log2(e) for cell gate g) into the output so
// kernel B can use raw v_exp_f32 (exp2) activations.
// ---------------------------------------------------------------------------
__global__ __launch_bounds__(256) void xproj_kernel(
    const float* __restrict__ x, const float* __restrict__ W,
    const float* __restrict__ b_ih, const float* __restrict__ b_hh,
    float* __restrict__ xg)
{
    __shared__ __align__(16) float4 ws4[H4 * NF4];   // 9.6 KB

    const int tid = threadIdx.x;
    const float4* __restrict__ w4 = (const float4*)W;
    for (int k = tid; k < H4 * NF4; k += 256)
        ws4[k] = w4[k];
    __syncthreads();

    const int  lane = tid & 3;
    const int  quad = tid >> 2;
    const long row0 = (long)blockIdx.x * RPB + (long)quad * 2;

    const float4* __restrict__ x0 = (const float4*)x + row0 * NF4;
    const float4* __restrict__ x1 = x0 + NF4;

    float acc0[H4], acc1[H4];
#pragma unroll
    for (int g = 0; g < H4; ++g) { acc0[g] = 0.f; acc1[g] = 0.f; }

    // main loop: i = 0..17, k = 4i+lane <= 71+3 < 75 -> no guard needed
#pragma unroll 3
    for (int i = 0; i < 18; ++i) {
        const int k = 4 * i + lane;
        float4 xa = x0[k];
        float4 xb = x1[k];
#pragma unroll
        for (int g = 0; g < H4; ++g) {
            float4 wv = ws4[g * NF4 + k];
            acc0[g] = dot4acc(xa, wv, acc0[g]);
            acc1[g] = dot4acc(xb, wv, acc1[g]);
        }
    }
    // epilogue: i = 18 -> k = 72+lane, valid only for lane < 3
    {
        const int k = 72 + lane;
        if (k < NF4) {
            float4 xa = x0[k];
            float4 xb = x1[k];
#pragma unroll
            for (int g = 0; g < H4; ++g) {
                float4 wv = ws4[g * NF4 + k];
                acc0[g] = dot4acc(xa, wv, acc0[g]);
                acc1[g] = dot4acc(xb, wv, acc1[g]);
            }
        }
    }

    // quad-local butterfly reduction (xor 1, xor 2 stay within the quad)
#pragma unroll
    for (int g = 0; g < H4; ++g) {
        acc0[g] += __shfl_xor(acc0[g], 1);
        acc0[g] += __shfl_xor(acc0[g], 2);
        acc1[g] += __shfl_xor(acc1[g], 1);
        acc1[g] += __shfl_xor(acc1[g], 2);
    }

    // lane l owns gate rows {2l, 2l+1} = slot l of unit 0 and unit 1.
    // gate order i i f f g g o o: slot 2 (rows 4,5) is the cell gate -> 2*log2e
    const float b0 = b_ih[2 * lane]     + b_hh[2 * lane];
    const float b1 = b_ih[2 * lane + 1] + b_hh[2 * lane + 1];
    const float sc = (lane == 2) ? L2E2 : L2E;

    // layout: xg[row*8 + u*4 + s]
    xg[row0 * 8 + lane]           = (acc0[2 * lane]     + b0) * sc;  // u=0
    xg[row0 * 8 + 4 + lane]       = (acc0[2 * lane + 1] + b1) * sc;  // u=1
    xg[(row0 + 1) * 8 + lane]     = (acc1[2 * lane]     + b0) * sc;
    xg[(row0 + 1) * 8 + 4 + lane] = (acc1[2 * lane + 1] + b1) * sc;
}

// ---------------------------------------------------------------------------
// Kernel B (v2): 2-lane-per-element LSTM scan.
// lane 2e+u owns hidden unit u of batch element e. The two units are
// independent through the whole activation stage; they couple only in the
// gate pre-activation, where the partner's h arrives via one DPP quad-perm
// swap. This HALVES the per-wave transcendental count (the issue-bound
// resource at 1 wave/SIMD): ~20 trans/step instead of 40.
// Weight columns are pre-swapped per-lane (wa = coeff of own h, wb = coeff
// of partner h), so the inner loop is select-free and identical across lanes.
// Gate pre-activations arrive pre-scaled by log2e (2*log2e for cell gate),
// so activations are exp2-direct: sig = rcp(1+exp2(-x)), tanh = 1-2*rcp(1+exp2(x)).
// ---------------------------------------------------------------------------
__global__ __launch_bounds__(64) void lstm_seq_kernel(
    const float* __restrict__ xg,
    const float* __restrict__ h0in, const float* __restrict__ c0in,
    const float* __restrict__ Whh0, const float* __restrict__ Wih1,
    const float* __restrict__ Whh1, const float* __restrict__ bih1,
    const float* __restrict__ bhh1, const float* __restrict__ Wlin,
    const float* __restrict__ blin, float* __restrict__ out)
{
    const int gid   = blockIdx.x * 64 + threadIdx.x;   // 0..2047
    const int e_raw = gid >> 1;
    const int u     = gid & 1;
    const bool wr   = (e_raw < BATCH) && (u == 0);
    const int  e    = (e_raw < BATCH) ? e_raw : (BATCH - 1);  // clamp: compute, no store

    // Per-lane weights: slot s in {i,f,g,o} -> gate row 2s+u.
    // wa* multiplies OWN h, wb* multiplies PARTNER h (column swap folded in).
    float wa0[4], wb0[4], wa1i[4], wb1i[4], wa1h[4], wb1h[4], bs1[4];
#pragma unroll
    for (int s = 0; s < 4; ++s) {
        const int   row = 2 * s + u;
        const float f   = (s == 2) ? L2E2 : L2E;
        wa0[s]  = Whh0[row * 2 + u]       * f;
        wb0[s]  = Whh0[row * 2 + (1 - u)] * f;
        wa1i[s] = Wih1[row * 2 + u]       * f;
        wb1i[s] = Wih1[row * 2 + (1 - u)] * f;
        wa1h[s] = Whh1[row * 2 + u]       * f;
        wb1h[s] = Whh1[row * 2 + (1 - u)] * f;
        bs1[s]  = (bih1[row] + bhh1[row]) * f;
    }

    // Initial state (inputs are [LAYERS, B, H]); own unit only.
    float h0 = h0in[2 * e + u];
    float c0 = c0in[2 * e + u];
    float h1 = h0in[2 * BATCH + 2 * e + u];
    float c1 = c0in[2 * BATCH + 2 * e + u];

    // step input: one float4 (i,f,g,o for own unit), wave reads 1KB contiguous
    const float4* __restrict__ xq = (const float4*)xg;
    float4 pre[4];
#pragma unroll
    for (int t = 0; t < 4; ++t)
        pre[t] = xq[((long)t * BATCH + e) * 2 + u];

    // Layer-1 partial gates (h1-dependent half), hoisted across steps.
    float h1o = swap1(h1);
    float p[4];
#pragma unroll
    for (int s = 0; s < 4; ++s)
        p[s] = bs1[s] + h1 * wa1h[s] + h1o * wb1h[s];

#pragma unroll 4
    for (int t = 0; t < T_STEPS; ++t) {
        const int sl = t & 3;
        const float4 xv = pre[sl];
        if (t + 4 < T_STEPS)
            pre[sl] = xq[((long)(t + 4) * BATCH + e) * 2 + u];

        // ----- layer 0 --------------------------------------------------
        const float h0o = swap1(h0);
        const float gi = xv.x + h0 * wa0[0] + h0o * wb0[0];
        const float gf = xv.y + h0 * wa0[1] + h0o * wb0[1];
        const float gg = xv.z + h0 * wa0[2] + h0o * wb0[2];
        const float go = xv.w + h0 * wa0[3] + h0o * wb0[3];
        c0 = sig2(gf) * c0 + sig2(gi) * tanh2(gg);
        h0 = sig2(go) * tanh2(c0 * L2E2);

        // ----- layer 1: q = p (precomputed) + h0-dependent half ---------
        const float h0n = swap1(h0);
        const float qi = p[0] + h0 * wa1i[0] + h0n * wb1i[0];
        const float qf = p[1] + h0 * wa1i[1] + h0n * wb1i[1];
        const float qg = p[2] + h0 * wa1i[2] + h0n * wb1i[2];
        const float qo = p[3] + h0 * wa1i[3] + h0n * wb1i[3];
        c1 = sig2(qf) * c1 + sig2(qi) * tanh2(qg);
        h1 = sig2(qo) * tanh2(c1 * L2E2);

        // hoist next step's h1-dependent layer-1 partials
        const float h1n = swap1(h1);
#pragma unroll
        for (int s = 0; s < 4; ++s)
            p[s] = bs1[s] + h1 * wa1h[s] + h1n * wb1h[s];
    }

    // unconditional swap (all lanes active), conditional store
    const float h1b = swap1(h1);
    if (wr)
        out[e] = h1 * Wlin[0] + h1b * Wlin[1] + blin[0];
}

extern "C" void kernel_launch(void* const* d_in, const int* in_sizes, int n_in,
                              void* d_out, int out_size, void* d_ws, size_t ws_size,
                              hipStream_t stream) {
    const float* x      = (const float*)d_in[0];
    const float* h0     = (const float*)d_in[1];
    const float* c0     = (const float*)d_in[2];
    const float* W_ih0  = (const float*)d_in[3];
    const float* W_hh0  = (const float*)d_in[4];
    const float* b_ih0  = (const float*)d_in[5];
    const float* b_hh0  = (const float*)d_in[6];
    const float* W_ih1  = (const float*)d_in[7];
    const float* W_hh1  = (const float*)d_in[8];
    const float* b_ih1  = (const float*)d_in[9];
    const float* b_hh1  = (const float*)d_in[10];
    const float* W_lin  = (const float*)d_in[11];
    const float* b_lin  = (const float*)d_in[12];
    float* out = (float*)d_out;
    float* xg  = (float*)d_ws;   // T*B*8 floats = 8.192 MB

    xproj_kernel<<<NBLK, 256, 0, stream>>>(x, W_ih0, b_ih0, b_hh0, xg);
    lstm_seq_kernel<<<(2 * BATCH + 63) / 64, 64, 0, stream>>>(
        xg, h0, c0, W_hh0, W_ih1, W_hh1, b_ih1, b_hh1, W_lin, b_lin, out);
}